// Round 3
// baseline (27710.358 us; speedup 1.0000x reference)
//
#include <hip/hip_runtime.h>

#define LL 1024
#define NBLK 256
#define NTHR 512

typedef __attribute__((ext_vector_type(8))) __bf16 bf16x8;
typedef __attribute__((ext_vector_type(4))) __bf16 bf16x4;
typedef __attribute__((ext_vector_type(16))) float f32x16;

// All inputs/outputs are FLOAT32. MFMA core runs bf16 (f32 accumulate).
__device__ __bf16 g_trg[128 * 1024 * 256];     // 64 MB
__device__ __bf16 g_wih[4096 * 256];           // 2 MB
__device__ __bf16 g_whh[4096 * 1024];          // 8 MB
__device__ __bf16 g_wout[256 * 1024];          // 0.5 MB
// Write-once h ring: [t(1024)][group(4)][kc(128)][m(32)][8] bf16 = 268 MB.
// Fresh addresses every step -> readers use plain cached loads, no invalidates.
// Cross-replay staleness handled by entry fence + flag protocol.
// Also read by the deferred out_proj kernel after the persistent kernel ends.
__device__ __bf16 g_ring[(size_t)1024 * 4 * 32768];
// Per-(step, group, block, wave) publish flags: [t][p][q][w]. Write-once per
// step, distinct dword per writer. Reader wave w' polls the 64 flags covering
// blocks q in [8w',8w'+8) -- one flag per lane, contiguous 256 B.
__device__ unsigned int g_flag[1024 * 4 * 64 * 8];   // 8 MB, zeroed each launch

__device__ __forceinline__ float sigm(float x) { return 1.f / (1.f + __expf(-x)); }
__device__ __forceinline__ float tanh_(float x) {
  x = fminf(fmaxf(x, -15.f), 15.f);
  float e = __expf(2.f * x);
  return (e - 1.f) / (e + 1.f);
}

__global__ void zero_flag() {
  int i = blockIdx.x * blockDim.x + threadIdx.x;   // grid 8192x256 = 2097152
  g_flag[i] = 0u;
}

__global__ void cvt4(const float* __restrict__ s, __bf16* __restrict__ d, int n4) {
  int i = blockIdx.x * blockDim.x + threadIdx.x;
  if (i < n4) {
    float4 v = ((const float4*)s)[i];
    bf16x4 o;
    o[0] = (__bf16)v.x; o[1] = (__bf16)v.y; o[2] = (__bf16)v.z; o[3] = (__bf16)v.w;
    ((bf16x4*)d)[i] = o;
  }
}

// Persistent LSTM decoder. Grid: 256 blocks = P(4 batch groups of 32 rows) x
// Q(64 col-blocks of 16 h-cols). Block: 8 waves, 8-way K-split: wave w owns
// h-k [w*128,(w+1)*128) + x-k [w*32,(w+1)*32) and computes BOTH 32-col tiles
// from one A fragment. Partials reduced via ds_add_f32 into one zsum[32][80]
// (10.2 KB LDS -- the 8-buffer variant blew the 64 KB static LDS limit).
// Publish: per-thread h packed to u32 via lane-pair shfl, even lanes store
// (agent scope), each wave drains its own store and sets its own flag.
// Out-projection deferred to out_proj. gid swizzle co-locates each group on
// 2 XCDs (perf heuristic only; correctness placement-independent).
__global__ __launch_bounds__(NTHR, 2) void lstm_persist(
    const float* __restrict__ b_ih, const float* __restrict__ b_hh)
{
  const int tid = threadIdx.x;
  const int lane = tid & 63;
  const int w = tid >> 6;        // wave 0..7 = K-split id
  const int gid = blockIdx.x;
  const int p = (gid & 7) >> 1;                // batch group -> XCD pair {2p,2p+1}
  const int q = ((gid >> 3) << 1) | (gid & 1); // col block 0..63
  const int m = lane & 31;
  const int khalf = (lane >> 5) << 3;   // 0 or 8

  // stride 80 -> bank = (16*row + col)%32 -> exactly 2-way on all accesses (free)
  __shared__ float zsum[32][80];        // 10.2 KB: shared K-split accumulator

  // One-time invalidate of stale L1/L2 lines from a previous replay.
  __builtin_amdgcn_fence(__ATOMIC_ACQUIRE, "agent");

  // ---- B fragments (weights) -> registers, kept for whole kernel ----
  // tile0: block-local gate cols 0..31 (gates i,f); tile1: 32..63 (gates g,o)
  const int colb = (q << 4) + (m & 15);
  const int grow0 = ((m >> 4) << 10) + colb;         // gate 0/1 row
  const int grow1 = ((2 + (m >> 4)) << 10) + colb;   // gate 2/3 row

  bf16x8 bR0[8], bR1[8], bX0[2], bX1[2];
  #pragma unroll
  for (int s = 0; s < 8; ++s) {            // recurrent slices, k in [w*128, ...)
    int k = (w << 7) + (s << 4) + khalf;
    bR0[s] = *(const bf16x8*)(g_whh + grow0 * 1024 + k);
    bR1[s] = *(const bf16x8*)(g_whh + grow1 * 1024 + k);
  }
  #pragma unroll
  for (int s = 0; s < 2; ++s) {            // input slices, k in [w*32, ...)
    int k = (w << 5) + (s << 4) + khalf;
    bX0[s] = *(const bf16x8*)(g_wih + grow0 * 256 + k);
    bX1[s] = *(const bf16x8*)(g_wih + grow1 * 256 + k);
  }

  // ---- elementwise role: thread <-> (batch row em, h-col ej) ----
  const int em = tid >> 4;             // 0..31  (= 4*w + (lane>>4))
  const int ej = tid & 15;             // 0..15
  const int hcol = (q << 4) + ej;
  float bias0 = b_ih[hcol]        + b_hh[hcol];
  float bias1 = b_ih[1024 + hcol] + b_hh[1024 + hcol];
  float bias2 = b_ih[2048 + hcol] + b_hh[2048 + hcol];
  float bias3 = b_ih[3072 + hcol] + b_hh[3072 + hcol];

  // ring element chunk for this thread's h value: c in [0,128)
  const int rc = (q << 1) + (ej >> 3);
  const int ejlo = ej & 7;

  float cst = 0.f;
  f32x16 acc0, acc1;
  #pragma unroll
  for (int r = 0; r < 16; ++r) { acc0[r] = 0.f; acc1[r] = 0.f; }

  // zero the shared accumulator once; steady-state re-zeroing is done by the
  // elementwise readers (each zeroes exactly the 4 cells it consumed).
  for (int i = tid; i < 32 * 80; i += NTHR) ((float*)zsum)[i] = 0.f;
  __syncthreads();

  const size_t trgbase = (size_t)(((p << 5) + m) << 10);

  #pragma unroll 1
  for (int t = 0; t < LL; ++t) {
    // ---- pre-wait: x-projection MFMAs (h-independent) ----
    {
      int tx = (t == 0) ? 0 : (t - 1);   // teacher forcing shift
      const __bf16* trow = g_trg + ((trgbase + tx) << 8);
      bf16x8 ax0 = *(const bf16x8*)(trow + (w << 5) + khalf);
      bf16x8 ax1 = *(const bf16x8*)(trow + (w << 5) + 16 + khalf);
      acc0 = __builtin_amdgcn_mfma_f32_32x32x16_bf16(ax0, bX0[0], acc0, 0, 0, 0);
      acc1 = __builtin_amdgcn_mfma_f32_32x32x16_bf16(ax0, bX1[0], acc1, 0, 0, 0);
      acc0 = __builtin_amdgcn_mfma_f32_32x32x16_bf16(ax1, bX0[1], acc0, 0, 0, 0);
      acc1 = __builtin_amdgcn_mfma_f32_32x32x16_bf16(ax1, bX1[1], acc1, 0, 0, 0);
    }
    // ---- per-wave poll: 64 flags (8 blocks x 8 waves), one per lane ----
    if (t > 0) {
      unsigned int* fp = g_flag + ((((t - 1) << 2) + p) << 9) + (w << 6) + lane;
      unsigned f = __hip_atomic_load(fp, __ATOMIC_RELAXED, __HIP_MEMORY_SCOPE_AGENT);
      int spins = 0;
      while (__any(f == 0u)) {
        __builtin_amdgcn_s_sleep(1);
        f = __hip_atomic_load(fp, __ATOMIC_RELAXED, __HIP_MEMORY_SCOPE_AGENT);
        if (++spins > 30000) break;   // safety bailout
      }
      // ---- recurrent GEMM: z += h_{t-1} @ w_hh^T (cached ring loads) ----
      const __bf16* rrd = g_ring + (size_t)(t - 1) * 131072 + (p << 15);
      #pragma unroll
      for (int s = 0; s < 8; ++s) {
        int k0 = (w << 7) + (s << 4);
        bf16x8 a = *(const bf16x8*)(rrd + ((k0 + khalf) << 5) + (m << 3));
        acc0 = __builtin_amdgcn_mfma_f32_32x32x16_bf16(a, bR0[s], acc0, 0, 0, 0);
        acc1 = __builtin_amdgcn_mfma_f32_32x32x16_bf16(a, bR1[s], acc1, 0, 0, 0);
      }
    }
    // ---- reduce K-split partials: ds_add into zsum ----
    // (C/D: col=lane&31, row=(r&3)+8*(r>>2)+4*(lane>>5))
    #pragma unroll
    for (int r = 0; r < 16; ++r) {
      int row = (r & 3) + ((r >> 2) << 3) + ((lane >> 5) << 2);
      atomicAdd(&zsum[row][m],      acc0[r]);  acc0[r] = 0.f;
      atomicAdd(&zsum[row][32 + m], acc1[r]);  acc1[r] = 0.f;
    }
    __syncthreads();     // (B) all waves' adds visible

    // ---- gates + state update; publish h directly from registers ----
    {
      float zi = zsum[em][ej]      + bias0;
      float zf = zsum[em][16 + ej] + bias1;
      float zg = zsum[em][32 + ej] + bias2;
      float zo = zsum[em][48 + ej] + bias3;
      zsum[em][ej] = 0.f; zsum[em][16 + ej] = 0.f;
      zsum[em][32 + ej] = 0.f; zsum[em][48 + ej] = 0.f;
      cst = sigm(zf) * cst + sigm(zi) * tanh_(zg);
      float h = sigm(zo) * tanh_(cst);
      __bf16 hb = (__bf16)h;
      unsigned hu = (unsigned)*(unsigned short*)&hb;
      unsigned pu = (unsigned)__shfl_xor((int)hu, 1);
      if ((ej & 1) == 0) {
        unsigned word = hu | (pu << 16);   // little-endian: ejlo even at low half
        unsigned* dst = (unsigned*)(g_ring + (size_t)t * 131072 + (p << 15))
                        + (rc << 7) + (em << 2) + (ejlo >> 1);
        __hip_atomic_store(dst, word, __ATOMIC_RELAXED, __HIP_MEMORY_SCOPE_AGENT);
      }
    }
    // ---- per-wave: drain own store, set own flag (before block barrier) ----
    asm volatile("s_waitcnt vmcnt(0)" ::: "memory");
    if (lane == 0) {
      __hip_atomic_store(g_flag + (((t << 2) + p) << 9) + (q << 3) + w, 1u,
                         __ATOMIC_RELAXED, __HIP_MEMORY_SCOPE_AGENT);
    }
    __syncthreads();     // (C') zsum zeroing complete before next step's adds
  }
}

// Deferred out-projection: out[b,t,:] = h_t[b,:] @ w_out^T + b_out.
// Grid: 256 blocks = tc(64 chunks of 16 t) x p(4). 8 waves; wave w = out cols
// [w*32,(w+1)*32), full K=1024. h_t staged in LDS once per t (64 KB, shared by
// all 8 waves); w_out streamed from L2 (hot, 512 KB total).
__global__ __launch_bounds__(NTHR, 2) void out_proj(
    const float* __restrict__ b_out, float* __restrict__ out)
{
  const int tid = threadIdx.x;
  const int lane = tid & 63;
  const int w = tid >> 6;
  const int m = lane & 31;
  const int khalf = (lane >> 5) << 3;
  const int gid = blockIdx.x;      // 256
  const int p = gid & 3;
  const int tc = gid >> 2;         // 0..63

  __shared__ __align__(16) __bf16 hbuf[32768];   // 64 KB = one h_t slab

  const float ob = b_out[(w << 5) + m];
  const __bf16* brow = g_wout + ((w << 5) + m) * 1024 + khalf;

  #pragma unroll 1
  for (int ti = 0; ti < 16; ++ti) {
    const int t = (tc << 4) + ti;
    const bf16x8* src = (const bf16x8*)(g_ring + (size_t)t * 131072 + (p << 15));
    __syncthreads();               // hbuf free (previous iteration's reads done)
    #pragma unroll
    for (int i = 0; i < 8; ++i)
      ((bf16x8*)hbuf)[(tid << 3) + i] = src[(tid << 3) + i];
    __syncthreads();

    f32x16 aA, aB;
    #pragma unroll
    for (int r = 0; r < 16; ++r) { aA[r] = 0.f; aB[r] = 0.f; }
    #pragma unroll
    for (int s = 0; s < 64; s += 2) {
      bf16x8 a0 = *(const bf16x8*)(hbuf + (((s << 4) + khalf) << 5) + (m << 3));
      bf16x8 a1 = *(const bf16x8*)(hbuf + ((((s + 1) << 4) + khalf) << 5) + (m << 3));
      bf16x8 b0 = *(const bf16x8*)(brow + (s << 4));
      bf16x8 b1 = *(const bf16x8*)(brow + ((s + 1) << 4));
      aA = __builtin_amdgcn_mfma_f32_32x32x16_bf16(a0, b0, aA, 0, 0, 0);
      aB = __builtin_amdgcn_mfma_f32_32x32x16_bf16(a1, b1, aB, 0, 0, 0);
    }
    #pragma unroll
    for (int r = 0; r < 16; ++r) {
      int row = (r & 3) + ((r >> 2) << 3) + ((lane >> 5) << 2);
      out[((((size_t)((p << 5) + row) << 10) + t) << 8) + (w << 5) + m] = aA[r] + aB[r] + ob;
    }
  }
}

extern "C" void kernel_launch(void* const* d_in, const int* in_sizes, int n_in,
                              void* d_out, int out_size, void* d_ws, size_t ws_size,
                              hipStream_t stream) {
  const float* trg   = (const float*)d_in[0];
  const float* w_ih  = (const float*)d_in[1];
  const float* w_hh  = (const float*)d_in[2];
  const float* b_ih  = (const float*)d_in[3];
  const float* b_hh  = (const float*)d_in[4];
  const float* w_out = (const float*)d_in[5];
  const float* b_out = (const float*)d_in[6];

  __bf16 *p_trg, *p_wih, *p_whh, *p_wout;
  hipGetSymbolAddress((void**)&p_trg,  HIP_SYMBOL(g_trg));
  hipGetSymbolAddress((void**)&p_wih,  HIP_SYMBOL(g_wih));
  hipGetSymbolAddress((void**)&p_whh,  HIP_SYMBOL(g_whh));
  hipGetSymbolAddress((void**)&p_wout, HIP_SYMBOL(g_wout));

  cvt4<<<dim3(33554432 / 4 / 256), dim3(256), 0, stream>>>(trg,   p_trg,  33554432 / 4);
  cvt4<<<dim3(1048576  / 4 / 256), dim3(256), 0, stream>>>(w_ih,  p_wih,  1048576  / 4);
  cvt4<<<dim3(4194304  / 4 / 256), dim3(256), 0, stream>>>(w_hh,  p_whh,  4194304  / 4);
  cvt4<<<dim3(262144   / 4 / 256), dim3(256), 0, stream>>>(w_out, p_wout, 262144   / 4);
  zero_flag<<<dim3(8192), dim3(256), 0, stream>>>();

  lstm_persist<<<dim3(NBLK), dim3(NTHR), 0, stream>>>(b_ih, b_hh);
  out_proj<<<dim3(NBLK), dim3(NTHR), 0, stream>>>(b_out, (float*)d_out);
}

// Round 4
// 4386.728 us; speedup vs baseline: 6.3169x; 6.3169x over previous
//
#include <hip/hip_runtime.h>

#define LL 1024
#define NBLK 256
#define NTHR 512

typedef __attribute__((ext_vector_type(8))) __bf16 bf16x8;
typedef __attribute__((ext_vector_type(4))) __bf16 bf16x4;
typedef __attribute__((ext_vector_type(16))) float f32x16;

// All inputs/outputs are FLOAT32. MFMA core runs bf16 (f32 accumulate).
__device__ __bf16 g_trg[128 * 1024 * 256];     // 64 MB
__device__ __bf16 g_wih[4096 * 256];           // 2 MB
__device__ __bf16 g_whh[4096 * 1024];          // 8 MB
__device__ __bf16 g_wout[256 * 1024];          // 0.5 MB
// Write-once h ring: [t(1024)][group(4)][kc(128)][m(32)][8] bf16 = 268 MB.
// Fresh addresses every step -> readers use plain cached loads, no invalidates.
// Cross-replay staleness handled by entry fence + flag protocol.
// Also read by the deferred out_proj kernel after the persistent kernel ends.
__device__ __bf16 g_ring[(size_t)1024 * 4 * 32768];
// Per-(step, group, block, wave) publish flags: [t][p][q][w]. Write-once per
// step, distinct dword per writer. Reader wave w' polls the 64 flags covering
// blocks q in [8w',8w'+8) -- one flag per lane, contiguous 256 B.
__device__ unsigned int g_flag[1024 * 4 * 64 * 8];   // 8 MB, zeroed each launch

__device__ __forceinline__ float sigm(float x) { return 1.f / (1.f + __expf(-x)); }
__device__ __forceinline__ float tanh_(float x) {
  x = fminf(fmaxf(x, -15.f), 15.f);
  float e = __expf(2.f * x);
  return (e - 1.f) / (e + 1.f);
}

__global__ void zero_flag() {
  int i = blockIdx.x * blockDim.x + threadIdx.x;   // grid 8192x256 = 2097152
  g_flag[i] = 0u;
}

__global__ void cvt4(const float* __restrict__ s, __bf16* __restrict__ d, int n4) {
  int i = blockIdx.x * blockDim.x + threadIdx.x;
  if (i < n4) {
    float4 v = ((const float4*)s)[i];
    bf16x4 o;
    o[0] = (__bf16)v.x; o[1] = (__bf16)v.y; o[2] = (__bf16)v.z; o[3] = (__bf16)v.w;
    ((bf16x4*)d)[i] = o;
  }
}

// Persistent LSTM decoder. Grid: 256 blocks = P(4 batch groups of 32 rows) x
// Q(64 col-blocks of 16 h-cols). Block: 8 waves, 8-way K-split: wave w owns
// h-k [w*128,(w+1)*128) + x-k [w*32,(w+1)*32) and computes BOTH 32-col tiles
// from one A fragment. Reduction: TWO-PHASE plain stores into one
// zp[8][32][40] buffer (41 KB): phase0 = acc0 (gates i,f), phase1 = acc1
// (gates g,o). No LDS atomics (atomicAdd(float) on LDS = CAS loop -> R3's 4x
// regression). Col layout 2*(m&15)+(m>>4) -> reader loads are float2, all LDS
// accesses <=2-way (free).
// Publish: per-thread h packed to u32 via lane-pair shfl, even lanes store
// (agent scope), each wave drains its own stores and sets its own flag.
// Out-projection deferred to out_proj. gid swizzle co-locates each group on
// 2 XCDs (perf heuristic only; correctness placement-independent).
__global__ __launch_bounds__(NTHR, 2) void lstm_persist(
    const float* __restrict__ b_ih, const float* __restrict__ b_hh)
{
  const int tid = threadIdx.x;
  const int lane = tid & 63;
  const int w = tid >> 6;        // wave 0..7 = K-split id
  const int gid = blockIdx.x;
  const int p = (gid & 7) >> 1;                // batch group -> XCD pair {2p,2p+1}
  const int q = ((gid >> 3) << 1) | (gid & 1); // col block 0..63
  const int m = lane & 31;
  const int khalf = (lane >> 5) << 3;   // 0 or 8

  // stride 40 floats: writer b32 stores 2-way, reader float2 minimal -> free
  __shared__ float zp[8][32][40];       // 40,960 B

  // One-time invalidate of stale L1/L2 lines from a previous replay.
  __builtin_amdgcn_fence(__ATOMIC_ACQUIRE, "agent");

  // ---- B fragments (weights) -> registers, kept for whole kernel ----
  // tile0 (acc0): block-local gate cols = i(m<16), f(m>=16)
  // tile1 (acc1): g(m<16), o(m>=16)
  const int colb = (q << 4) + (m & 15);
  const int grow0 = ((m >> 4) << 10) + colb;         // gate 0/1 row
  const int grow1 = ((2 + (m >> 4)) << 10) + colb;   // gate 2/3 row

  bf16x8 bR0[8], bR1[8], bX0[2], bX1[2];
  #pragma unroll
  for (int s = 0; s < 8; ++s) {            // recurrent slices, k in [w*128, ...)
    int k = (w << 7) + (s << 4) + khalf;
    bR0[s] = *(const bf16x8*)(g_whh + grow0 * 1024 + k);
    bR1[s] = *(const bf16x8*)(g_whh + grow1 * 1024 + k);
  }
  #pragma unroll
  for (int s = 0; s < 2; ++s) {            // input slices, k in [w*32, ...)
    int k = (w << 5) + (s << 4) + khalf;
    bX0[s] = *(const bf16x8*)(g_wih + grow0 * 256 + k);
    bX1[s] = *(const bf16x8*)(g_wih + grow1 * 256 + k);
  }

  // ---- elementwise role: thread <-> (batch row em, h-col ej) ----
  const int em = tid >> 4;             // 0..31
  const int ej = tid & 15;             // 0..15
  const int hcol = (q << 4) + ej;
  float bias_i = b_ih[hcol]        + b_hh[hcol];
  float bias_f = b_ih[1024 + hcol] + b_hh[1024 + hcol];
  float bias_g = b_ih[2048 + hcol] + b_hh[2048 + hcol];
  float bias_o = b_ih[3072 + hcol] + b_hh[3072 + hcol];

  // ring element chunk for this thread's h value
  const int rc = (q << 1) + (ej >> 3);
  const int ejlo = ej & 7;

  // writer column in zp (interleaved so reader gets float2 pairs)
  const int wcol = ((m & 15) << 1) + (m >> 4);

  float cst = 0.f;
  f32x16 acc0, acc1;
  #pragma unroll
  for (int r = 0; r < 16; ++r) { acc0[r] = 0.f; acc1[r] = 0.f; }

  const size_t trgbase = (size_t)(((p << 5) + m) << 10);

  #pragma unroll 1
  for (int t = 0; t < LL; ++t) {
    // ---- pre-wait: x-projection MFMAs (h-independent) ----
    {
      int tx = (t == 0) ? 0 : (t - 1);   // teacher forcing shift
      const __bf16* trow = g_trg + ((trgbase + tx) << 8);
      bf16x8 ax0 = *(const bf16x8*)(trow + (w << 5) + khalf);
      bf16x8 ax1 = *(const bf16x8*)(trow + (w << 5) + 16 + khalf);
      acc0 = __builtin_amdgcn_mfma_f32_32x32x16_bf16(ax0, bX0[0], acc0, 0, 0, 0);
      acc1 = __builtin_amdgcn_mfma_f32_32x32x16_bf16(ax0, bX1[0], acc1, 0, 0, 0);
      acc0 = __builtin_amdgcn_mfma_f32_32x32x16_bf16(ax1, bX0[1], acc0, 0, 0, 0);
      acc1 = __builtin_amdgcn_mfma_f32_32x32x16_bf16(ax1, bX1[1], acc1, 0, 0, 0);
    }
    // ---- per-wave poll: 64 flags (8 blocks x 8 waves), one per lane ----
    if (t > 0) {
      unsigned int* fp = g_flag + ((((t - 1) << 2) + p) << 9) + (w << 6) + lane;
      unsigned f = __hip_atomic_load(fp, __ATOMIC_RELAXED, __HIP_MEMORY_SCOPE_AGENT);
      int spins = 0;
      while (__any(f == 0u)) {
        __builtin_amdgcn_s_sleep(1);
        f = __hip_atomic_load(fp, __ATOMIC_RELAXED, __HIP_MEMORY_SCOPE_AGENT);
        if (++spins > 30000) break;   // safety bailout
      }
      // ---- recurrent GEMM: z += h_{t-1} @ w_hh^T (cached ring loads) ----
      const __bf16* rrd = g_ring + (size_t)(t - 1) * 131072 + (p << 15);
      #pragma unroll
      for (int s = 0; s < 8; ++s) {
        int k0 = (w << 7) + (s << 4);
        bf16x8 a = *(const bf16x8*)(rrd + ((k0 + khalf) << 5) + (m << 3));
        acc0 = __builtin_amdgcn_mfma_f32_32x32x16_bf16(a, bR0[s], acc0, 0, 0, 0);
        acc1 = __builtin_amdgcn_mfma_f32_32x32x16_bf16(a, bR1[s], acc1, 0, 0, 0);
      }
    }
    // ---- phase 0: dump acc0 (i,f) ----
    // (C/D: col=lane&31, row=(r&3)+8*(r>>2)+4*(lane>>5))
    #pragma unroll
    for (int r = 0; r < 16; ++r) {
      int row = (r & 3) + ((r >> 2) << 3) + ((lane >> 5) << 2);
      zp[w][row][wcol] = acc0[r];  acc0[r] = 0.f;
    }
    __syncthreads();     // (B) phase0 writes visible
    float zi = bias_i, zf = bias_f;
    #pragma unroll
    for (int s = 0; s < 8; ++s) {
      float2 v = *(const float2*)&zp[s][em][ej << 1];
      zi += v.x; zf += v.y;
    }
    __syncthreads();     // (C) phase0 reads done; buffer free
    // ---- phase 1: dump acc1 (g,o) ----
    #pragma unroll
    for (int r = 0; r < 16; ++r) {
      int row = (r & 3) + ((r >> 2) << 3) + ((lane >> 5) << 2);
      zp[w][row][wcol] = acc1[r];  acc1[r] = 0.f;
    }
    float si = sigm(zi);                 // overlaps phase1 LDS latency
    float cp = sigm(zf) * cst;
    __syncthreads();     // (D) phase1 writes visible
    float zg = bias_g, zo = bias_o;
    #pragma unroll
    for (int s = 0; s < 8; ++s) {
      float2 v = *(const float2*)&zp[s][em][ej << 1];
      zg += v.x; zo += v.y;
    }
    cst = cp + si * tanh_(zg);
    float h = sigm(zo) * tanh_(cst);
    // ---- publish h directly from registers ----
    {
      __bf16 hb = (__bf16)h;
      unsigned hu = (unsigned)*(unsigned short*)&hb;
      unsigned pu = (unsigned)__shfl_xor((int)hu, 1);
      if ((ej & 1) == 0) {
        unsigned word = hu | (pu << 16);   // little-endian: even ejlo at low half
        unsigned* dst = (unsigned*)(g_ring + (size_t)t * 131072 + (p << 15))
                        + (rc << 7) + (em << 2) + (ejlo >> 1);
        __hip_atomic_store(dst, word, __ATOMIC_RELAXED, __HIP_MEMORY_SCOPE_AGENT);
      }
    }
    // ---- per-wave: drain own stores, set own flag ----
    asm volatile("s_waitcnt vmcnt(0)" ::: "memory");
    if (lane == 0) {
      __hip_atomic_store(g_flag + (((t << 2) + p) << 9) + (q << 3) + w, 1u,
                         __ATOMIC_RELAXED, __HIP_MEMORY_SCOPE_AGENT);
    }
    __syncthreads();     // (E) phase1 reads done; zp free for next step
  }
}

// Deferred out-projection: out[b,t,:] = h_t[b,:] @ w_out^T + b_out.
// Grid: 256 blocks = tcb(8 chunks of 128 t) x oc(8 out-col tiles of 32) x p(4).
// 8 waves = 8-way K-split; wave w holds w_out fragments for k in
// [w*128,(w+1)*128) in REGISTERS (loaded once). A-fragments read directly from
// the ring (same pattern as persist's ring MFMAs) with 1-step prefetch.
// Single-phase LDS reduce of the 8 K-partials, coalesced 64B-run out stores.
__global__ __launch_bounds__(NTHR, 2) void out_proj(
    const float* __restrict__ b_out, float* __restrict__ out)
{
  const int tid = threadIdx.x;
  const int lane = tid & 63;
  const int w = tid >> 6;
  const int m = lane & 31;
  const int khalf = (lane >> 5) << 3;
  const int gid = blockIdx.x;      // 256
  const int p = gid & 3;
  const int oc = (gid >> 2) & 7;   // out-col tile (32 cols)
  const int tcb = gid >> 5;        // t chunk 0..7 (128 t each)

  __shared__ float zp[8][32][36];  // 36,864 B; (4*row+col)%32 -> 2-way (free)

  // ---- w_out B fragments in registers for the whole kernel ----
  bf16x8 bo[8];
  #pragma unroll
  for (int s = 0; s < 8; ++s)
    bo[s] = *(const bf16x8*)(g_wout + ((oc << 5) + m) * 1024 + (w << 7) + (s << 4) + khalf);

  const int em = tid >> 4;         // 0..31 batch row (elementwise role)
  const int c  = tid & 15;         // out cols c and c+16 within tile
  const float ob0 = b_out[(oc << 5) + c];
  const float ob1 = b_out[(oc << 5) + 16 + c];

  const int t0 = tcb << 7;
  bf16x8 a[8], an[8];
  {
    const __bf16* rrd = g_ring + (size_t)t0 * 131072 + (p << 15);
    #pragma unroll
    for (int s = 0; s < 8; ++s)
      a[s] = *(const bf16x8*)(rrd + (((w << 7) + (s << 4) + khalf) << 5) + (m << 3));
  }

  #pragma unroll 1
  for (int ti = 0; ti < 128; ++ti) {
    const int t = t0 + ti;
    // prefetch next t's A fragments (hides LLC RTT under reduce phases)
    if (ti < 127) {
      const __bf16* rrd = g_ring + (size_t)(t + 1) * 131072 + (p << 15);
      #pragma unroll
      for (int s = 0; s < 8; ++s)
        an[s] = *(const bf16x8*)(rrd + (((w << 7) + (s << 4) + khalf) << 5) + (m << 3));
    }
    f32x16 acc;
    #pragma unroll
    for (int r = 0; r < 16; ++r) acc[r] = 0.f;
    #pragma unroll
    for (int s = 0; s < 8; ++s)
      acc = __builtin_amdgcn_mfma_f32_32x32x16_bf16(a[s], bo[s], acc, 0, 0, 0);
    #pragma unroll
    for (int r = 0; r < 16; ++r) {
      int row = (r & 3) + ((r >> 2) << 3) + ((lane >> 5) << 2);
      zp[w][row][m] = acc[r];
    }
    __syncthreads();
    float o0 = ob0, o1 = ob1;
    #pragma unroll
    for (int s = 0; s < 8; ++s) {
      o0 += zp[s][em][c];
      o1 += zp[s][em][16 + c];
    }
    float* orow = out + ((((size_t)((p << 5) + em) << 10) + t) << 8) + (oc << 5);
    orow[c]      = o0;
    orow[16 + c] = o1;
    __syncthreads();     // WAR: reads done before next iteration's dump
    #pragma unroll
    for (int s = 0; s < 8; ++s) a[s] = an[s];
  }
}

extern "C" void kernel_launch(void* const* d_in, const int* in_sizes, int n_in,
                              void* d_out, int out_size, void* d_ws, size_t ws_size,
                              hipStream_t stream) {
  const float* trg   = (const float*)d_in[0];
  const float* w_ih  = (const float*)d_in[1];
  const float* w_hh  = (const float*)d_in[2];
  const float* b_ih  = (const float*)d_in[3];
  const float* b_hh  = (const float*)d_in[4];
  const float* w_out = (const float*)d_in[5];
  const float* b_out = (const float*)d_in[6];

  __bf16 *p_trg, *p_wih, *p_whh, *p_wout;
  hipGetSymbolAddress((void**)&p_trg,  HIP_SYMBOL(g_trg));
  hipGetSymbolAddress((void**)&p_wih,  HIP_SYMBOL(g_wih));
  hipGetSymbolAddress((void**)&p_whh,  HIP_SYMBOL(g_whh));
  hipGetSymbolAddress((void**)&p_wout, HIP_SYMBOL(g_wout));

  cvt4<<<dim3(33554432 / 4 / 256), dim3(256), 0, stream>>>(trg,   p_trg,  33554432 / 4);
  cvt4<<<dim3(1048576  / 4 / 256), dim3(256), 0, stream>>>(w_ih,  p_wih,  1048576  / 4);
  cvt4<<<dim3(4194304  / 4 / 256), dim3(256), 0, stream>>>(w_hh,  p_whh,  4194304  / 4);
  cvt4<<<dim3(262144   / 4 / 256), dim3(256), 0, stream>>>(w_out, p_wout, 262144   / 4);
  zero_flag<<<dim3(8192), dim3(256), 0, stream>>>();

  lstm_persist<<<dim3(NBLK), dim3(NTHR), 0, stream>>>(b_ih, b_hh);
  out_proj<<<dim3(NBLK), dim3(NTHR), 0, stream>>>(b_out, (float*)d_out);
}